// Round 12
// baseline (292.138 us; speedup 1.0000x reference)
//
#include <hip/hip_runtime.h>
#include <hip/hip_bf16.h>

#define BATCH 16
#define NV    20000
#define FIN   64
#define NCOUT 64
#define NK    16
#define TOTROWS  (BATCH * NV)      // 320000
#define NTILES   (TOTROWS / 16)    // 20000 row-tiles of 16

typedef __attribute__((ext_vector_type(8))) short bf16x8;   // 8 bf16 (4 VGPRs)
typedef __attribute__((ext_vector_type(4))) float f32x4;    // MFMA acc
typedef __attribute__((ext_vector_type(4))) unsigned short u16x4;
typedef __attribute__((ext_vector_type(4))) unsigned int u32x4;

__device__ __forceinline__ short f2b(float f) {
    __hip_bfloat16 h = __float2bfloat16(f);   // RTNE
    return __builtin_bit_cast(short, h);
}

// ---------------------------------------------------------------------------
// Pass A: one x-sweep, MFMA 16x16x32 bf16.  (EXACT round-1 kernel — best
// measured config across rounds 1/2/9/11: gemm+overhead ≈ 149 µs constant.)
//   p[row][c] = x[row]@Wx[:,c] + bias[c]  -> out (fp32)
//   z[row][c] = x[row]@(Wn/16)            -> ws  (bf16)
// ---------------------------------------------------------------------------
__global__ __launch_bounds__(256, 3) void convnet_gemm(
    const float* __restrict__ x,      // (320000, 64)
    const float* __restrict__ Wx,     // (64, 64)
    const float* __restrict__ Wn,     // (64, 64)
    const float* __restrict__ bias,   // (64)
    __hip_bfloat16* __restrict__ z,   // (320000, 64) bf16  [ws]
    float* __restrict__ out)          // (320000, 64) fp32  (gets p)
{
    const int lane = threadIdx.x & 63;
    const int m    = lane & 15;
    const int quad = lane >> 4;

    bf16x8 bf[8][2];
#pragma unroll
    for (int t = 0; t < 8; ++t) {
        const float* W = (t < 4) ? Wx : Wn;
        const float scale = (t < 4) ? 1.0f : (1.0f / 16.0f);
        const int c = 4 * m + (t & 3);
#pragma unroll
        for (int h = 0; h < 2; ++h) {
            bf16x8 fr;
#pragma unroll
            for (int j = 0; j < 8; ++j) {
                const int f = 32 * h + quad * 8 + j;
                fr[j] = f2b(W[f * NCOUT + c] * scale);
            }
            bf[t][h] = fr;
        }
    }
    float bias_q[4];
#pragma unroll
    for (int t = 0; t < 4; ++t) bias_q[t] = bias[4 * m + t];

    const int nwaves = (gridDim.x * blockDim.x) >> 6;   // 3072
    const int gw = (blockIdx.x * blockDim.x + threadIdx.x) >> 6;

    int rt = __builtin_amdgcn_readfirstlane(gw);
    const float* xt0 = x + (size_t)rt * (16 * FIN) + (size_t)m * FIN + quad * 8;
    float4 La0 = ((const float4*)xt0)[0];
    float4 La1 = ((const float4*)xt0)[1];
    float4 Lb0 = ((const float4*)(xt0 + 32))[0];
    float4 Lb1 = ((const float4*)(xt0 + 32))[1];

    for (;;) {
        bf16x8 af0, af1;
        af0[0] = f2b(La0.x); af0[1] = f2b(La0.y); af0[2] = f2b(La0.z); af0[3] = f2b(La0.w);
        af0[4] = f2b(La1.x); af0[5] = f2b(La1.y); af0[6] = f2b(La1.z); af0[7] = f2b(La1.w);
        af1[0] = f2b(Lb0.x); af1[1] = f2b(Lb0.y); af1[2] = f2b(Lb0.z); af1[3] = f2b(Lb0.w);
        af1[4] = f2b(Lb1.x); af1[5] = f2b(Lb1.y); af1[6] = f2b(Lb1.z); af1[7] = f2b(Lb1.w);

        const int rtn = rt + nwaves;
        const bool more = rtn < NTILES;
        float4 Na0, Na1, Nb0, Nb1;
        if (more) {
            const float* xn = x + (size_t)rtn * (16 * FIN) + (size_t)m * FIN + quad * 8;
            Na0 = ((const float4*)xn)[0];
            Na1 = ((const float4*)xn)[1];
            Nb0 = ((const float4*)(xn + 32))[0];
            Nb1 = ((const float4*)(xn + 32))[1];
        }

        f32x4 acc[8];
#pragma unroll
        for (int t = 0; t < 8; ++t) acc[t] = (f32x4){0.f, 0.f, 0.f, 0.f};
#pragma unroll
        for (int t = 0; t < 8; ++t)
            acc[t] = __builtin_amdgcn_mfma_f32_16x16x32_bf16(af0, bf[t][0], acc[t], 0, 0, 0);
#pragma unroll
        for (int t = 0; t < 8; ++t)
            acc[t] = __builtin_amdgcn_mfma_f32_16x16x32_bf16(af1, bf[t][1], acc[t], 0, 0, 0);

        const size_t rbase = (size_t)rt * 16 + quad * 4;
#pragma unroll
        for (int r = 0; r < 4; ++r) {
            const size_t orow = (rbase + r) * NCOUT + 4 * m;
            float4 o;
            o.x = acc[0][r] + bias_q[0];
            o.y = acc[1][r] + bias_q[1];
            o.z = acc[2][r] + bias_q[2];
            o.w = acc[3][r] + bias_q[3];
            *(float4*)(out + orow) = o;
            u16x4 zz;
            zz.x = (unsigned short)f2b(acc[4][r]);
            zz.y = (unsigned short)f2b(acc[5][r]);
            zz.z = (unsigned short)f2b(acc[6][r]);
            zz.w = (unsigned short)f2b(acc[7][r]);
            *(u16x4*)(z + orow) = zz;
        }

        if (!more) break;
        rt = __builtin_amdgcn_readfirstlane(rtn);
        La0 = Na0; La1 = Na1; Lb0 = Nb0; Lb1 = Nb1;
    }
}

// ---------------------------------------------------------------------------
// Pass B: out[b,v,:] += sum_k z[b, nbr[v,k]-1, :]  (idx==0 = zero pad).
// ROUND-12: discriminating test of the TA per-instr model. Wave = 8 rows;
// lane = (s=lane>>3 sub-row, c=lane&7 col-group). Gathers are u32x4
// (16 B/lane, wave = 8 z-rows x 128 B = 1 KB/instr): gather-instr count
// HALVES vs the 72-µs r2 shape at identical traffic. r8 proved this gather
// shape sustains ~3.95 TB/s; its regression was write amplification from
// strided stores — fixed here by a wave-private LDS transpose (row stride
// 68 floats: 16B-aligned, banks spread): accumulate in 8x8 layout, bounce
// 2 KB through LDS, read back in 4-row x 16-col layout -> out RMW read and
// store are clean wave-contiguous 1 KB instructions (WRITE = 80 MB).
// Out-reads issued before the gathers (cached, NOT nontemporal — r9 lesson).
// ---------------------------------------------------------------------------
__global__ __launch_bounds__(256, 6) void convnet_gather(
    const int* __restrict__ nbr,           // (20000, 16), values in [0, V]
    const __hip_bfloat16* __restrict__ z,  // (320000, 64) bf16
    float* __restrict__ out)               // (320000, 64) fp32, has p already
{
    __shared__ float lds[4][8 * 68];       // 8.5 KB: 4 waves x 8 rows x 68f

    const int tid  = (int)threadIdx.x;
    const int lane = tid & 63;
    const int w    = tid >> 6;             // wave in block
    const int s    = lane >> 3;            // sub-row 0..7 (gather layout)
    const int c    = lane & 7;             // col group (8 bf16 = 16 B)
    const int r0   = lane >> 4;            // row 0..3 (store layout)
    const int c2   = lane & 15;            // col group (4 f32 = 16 B)

    const int xcd  = blockIdx.x & 7;
    const int bi   = blockIdx.x >> 3;                        // 0..191
    const int wl   = bi * 4 + w;                             // 0..767
    const int WPX  = (gridDim.x >> 3) * 4;                   // 768 waves/xcd

    const int zcol   = c * 16;             // byte col offset (8 bf16)
    const int GROUPS = (2 * NV) / 8;       // 5000 groups per xcd (8 | NV)

    for (int g = wl; g < GROUPS; g += WPX) {
        const int gu = __builtin_amdgcn_readfirstlane(g);
        const int bl = (gu >= NV / 8) ? 1 : 0;
        const int b  = 2 * xcd + bl;
        const int v0 = gu * 8 - bl * NV;
        const int row0 = b * NV + v0;      // global out row of sub-row 0

        // out RMW reads in STORE layout, issued early (hide under gathers)
        float* op0 = out + (size_t)(row0 + r0) * NCOUT + 4 * c2;
        float* op1 = op0 + 4 * NCOUT;
        f32x4 ov0 = *(const f32x4*)op0;
        f32x4 ov1 = *(const f32x4*)op1;

        // neighbor ids for this lane's sub-row: 4x int4 (one 64B line/row).
        const int4* nb4 =
            (const int4*)((const char*)nbr + (size_t)(v0 + s) * (NK * 4));
        const int4 i0 = nb4[0];
        const int4 i1 = nb4[1];
        const int4 i2 = nb4[2];
        const int4 i3 = nb4[3];
        int id[NK];
        id[0]  = i0.x; id[1]  = i0.y; id[2]  = i0.z; id[3]  = i0.w;
        id[4]  = i1.x; id[5]  = i1.y; id[6]  = i1.z; id[7]  = i1.w;
        id[8]  = i2.x; id[9]  = i2.y; id[10] = i2.z; id[11] = i2.w;
        id[12] = i3.x; id[13] = i3.y; id[14] = i3.z; id[15] = i3.w;

        const char* zb = (const char*)z + (size_t)b * (NV * 128);  // batch base
        float a0 = 0.f, a1 = 0.f, a2 = 0.f, a3 = 0.f;
        float a4 = 0.f, a5 = 0.f, a6 = 0.f, a7 = 0.f;
#pragma unroll
        for (int k = 0; k < NK; ++k) {
            const int idx = id[k];
            int sel = idx - 1;
            sel = sel < 0 ? 0 : sel;       // clamp pad (row 0 read, masked)
            const u32x4 d =
                *(const u32x4*)(zb + (size_t)(unsigned)(sel * 128 + zcol));
            const unsigned d0 = idx ? d.x : 0u;
            const unsigned d1 = idx ? d.y : 0u;
            const unsigned d2 = idx ? d.z : 0u;
            const unsigned d3 = idx ? d.w : 0u;
            a0 += __builtin_bit_cast(float, d0 << 16);
            a1 += __builtin_bit_cast(float, d0 & 0xFFFF0000u);
            a2 += __builtin_bit_cast(float, d1 << 16);
            a3 += __builtin_bit_cast(float, d1 & 0xFFFF0000u);
            a4 += __builtin_bit_cast(float, d2 << 16);
            a5 += __builtin_bit_cast(float, d2 & 0xFFFF0000u);
            a6 += __builtin_bit_cast(float, d3 << 16);
            a7 += __builtin_bit_cast(float, d3 & 0xFFFF0000u);
        }

        // LDS transpose: write 8x8 layout (row stride 68f, 16B aligned)
        float* lw = &lds[w][s * 68 + c * 8];
        *(f32x4*)lw       = (f32x4){a0, a1, a2, a3};
        *(f32x4*)(lw + 4) = (f32x4){a4, a5, a6, a7};

        // read back in 4-row x 16-col store layout (wave-private: no barrier)
        const f32x4 t0 = *(const f32x4*)&lds[w][(r0)     * 68 + c2 * 4];
        const f32x4 t1 = *(const f32x4*)&lds[w][(r0 + 4) * 68 + c2 * 4];

        *(f32x4*)op0 = ov0 + t0;           // wave = 1 KB contiguous
        *(f32x4*)op1 = ov1 + t1;
    }
}

extern "C" void kernel_launch(void* const* d_in, const int* in_sizes, int n_in,
                              void* d_out, int out_size, void* d_ws, size_t ws_size,
                              hipStream_t stream) {
    const float* x    = (const float*)d_in[0];
    const float* Wx   = (const float*)d_in[1];
    const float* Wn   = (const float*)d_in[2];
    const float* bias = (const float*)d_in[3];
    const int*   nbr  = (const int*)d_in[4];
    float* out = (float*)d_out;

    __hip_bfloat16* z = (__hip_bfloat16*)d_ws;   // 40.96 MB (fits ws)

    hipLaunchKernelGGL(convnet_gemm, dim3(768), dim3(256), 0, stream,
                       x, Wx, Wn, bias, z, out);
    hipLaunchKernelGGL(convnet_gather, dim3(1536), dim3(256), 0, stream,
                       nbr, z, out);
}